// Round 4
// baseline (360.257 us; speedup 1.0000x reference)
//
#include <hip/hip_runtime.h>

typedef short s16x8 __attribute__((ext_vector_type(8)));
typedef short s16x4 __attribute__((ext_vector_type(4)));
typedef float f32x4 __attribute__((ext_vector_type(4)));

#define NB 16
#define NC 256
#define NL 4096
#define NH 1024
#define NE 128

// ws layout (bytes)
#define WS_YNT   0ull          // [B][L][C] bf16 transposed y   : 33554432
#define WS_PW1   33554432ull   // pw1 bf16 [1024][256]          : 524288
#define WS_PW2   34078720ull   // pw2 bf16 [256][1024]          : 524288
#define WS_AF    34603008ull   // a_film  [B][C] f32            : 16384
#define WS_BF    34619392ull   // b_film  [B][C] f32            : 16384
#define WS_SUMS  34635776ull   // [B][2] f32 sums               : 128

#define MFMA16(a, b, c) __builtin_amdgcn_mfma_f32_16x16x32_bf16((a), (b), (c), 0, 0, 0)

// Barrier that waits LDS ops only: global (vmcnt) register loads stay in
// flight across it. __syncthreads() would drain vmcnt(0) and expose full
// L2 latency of the weight prefetch 2x per chunk.
#define BARSYNC() asm volatile("s_waitcnt lgkmcnt(0)\n\ts_barrier" ::: "memory")

static __device__ __forceinline__ short f2bf(float f) {
    unsigned int u = __float_as_uint(f);
    u = (u + 0x7fffu + ((u >> 16) & 1u)) >> 16;
    return (short)u;
}
static __device__ __forceinline__ float bf2f(short s) {
    return __uint_as_float(((unsigned int)(unsigned short)s) << 16);
}

// ---------------- K0: weight convert + zero sums ----------------
__global__ __launch_bounds__(256) void k0_prep(const float* __restrict__ pw1,
                                               const float* __restrict__ pw2,
                                               short* __restrict__ pw1b,
                                               short* __restrict__ pw2b,
                                               float* __restrict__ sums) {
    int idx = blockIdx.x * 256 + threadIdx.x;
    if (idx < NH * NC) {
        pw1b[idx] = f2bf(pw1[idx]);
        pw2b[idx] = f2bf(pw2[idx]);
    }
    if (blockIdx.x == 0 && threadIdx.x < 32) sums[threadIdx.x] = 0.f;
}

// ---------------- K1: depthwise conv (circular) + transpose-store + stats ----
// grid: B * 4 * 64 blocks; tile = (b, 64 c, 64 l). 256 threads.
__global__ __launch_bounds__(256) void k1_dwconv(const float* __restrict__ x,
                                                 const float* __restrict__ dw_w,
                                                 const float* __restrict__ dw_b,
                                                 short* __restrict__ ynt,
                                                 float* __restrict__ sums) {
    __shared__ float xt[64][81];   // bank stride 81%32=17 (odd) -> <=2-way, free
    __shared__ float red1[4], red2[4];
    const int b = blockIdx.x >> 8;
    const int rem = blockIdx.x & 255;
    const int c0 = (rem >> 6) << 6;   // 4 c-blocks of 64
    const int l0 = (rem & 63) << 6;   // 64 l-blocks of 64
    const int t = threadIdx.x;

    // ---- stage 64 rows x 80 floats, coalesced float4 global loads ----
    const float* xb = x + ((size_t)(b * NC + c0)) * NL;
    {
#pragma unroll
        for (int j = 0; j < 5; ++j) {
            const int idx = t + 256 * j;
            const int row = idx / 20;
            const int col = idx - row * 20;
            const int lg = (l0 - 4 + col * 4) & (NL - 1);   // circular, 16B-aligned
            const float4 v = *(const float4*)(xb + (size_t)row * NL + lg);
            xt[row][col * 4 + 0] = v.x;
            xt[row][col * 4 + 1] = v.y;
            xt[row][col * 4 + 2] = v.z;
            xt[row][col * 4 + 3] = v.w;
        }
    }

    const int c = t & 63;       // lane == channel within tile
    const int w = t >> 6;       // wave id -> 16-l strip
    const float w0 = dw_w[(c0 + c) * 7 + 0], w1 = dw_w[(c0 + c) * 7 + 1],
                w2 = dw_w[(c0 + c) * 7 + 2], w3 = dw_w[(c0 + c) * 7 + 3],
                w4 = dw_w[(c0 + c) * 7 + 4], w5 = dw_w[(c0 + c) * 7 + 5],
                w6 = dw_w[(c0 + c) * 7 + 6];
    const float bb = dw_b[c0 + c];
    __syncthreads();

    float win0 = xt[c][w * 16 + 1], win1 = xt[c][w * 16 + 2], win2 = xt[c][w * 16 + 3],
          win3 = xt[c][w * 16 + 4], win4 = xt[c][w * 16 + 5], win5 = xt[c][w * 16 + 6],
          win6 = xt[c][w * 16 + 7];
    float s1 = 0.f, s2 = 0.f;
    short* yo = ynt + ((size_t)(b * NL + l0 + w * 16)) * NC + c0 + c;
#pragma unroll
    for (int i = 0; i < 16; ++i) {
        const float y = bb + w0 * win0 + w1 * win1 + w2 * win2 + w3 * win3 +
                        w4 * win4 + w5 * win5 + w6 * win6;
        s1 += y;
        s2 += y * y;
        yo[(size_t)i * NC] = f2bf(y);
        win0 = win1; win1 = win2; win2 = win3; win3 = win4; win4 = win5; win5 = win6;
        win6 = xt[c][w * 16 + i + 8];
    }
    for (int off = 32; off; off >>= 1) {
        s1 += __shfl_down(s1, off, 64);
        s2 += __shfl_down(s2, off, 64);
    }
    if ((t & 63) == 0) { red1[w] = s1; red2[w] = s2; }
    __syncthreads();
    if (t == 0) {
        atomicAdd(&sums[b * 2 + 0], red1[0] + red1[1] + red1[2] + red1[3]);
        atomicAdd(&sums[b * 2 + 1], red2[0] + red2[1] + red2[2] + red2[3]);
    }
}

// ---------------- K2: finalize stats + FiLM -> per-(b,c) affine --------------
__global__ __launch_bounds__(256) void k2_finalize(const float* __restrict__ tin,
                                                   const float* __restrict__ fw,
                                                   const float* __restrict__ fb,
                                                   const float* __restrict__ sums,
                                                   float* __restrict__ afilm,
                                                   float* __restrict__ bfilm) {
    const int b = blockIdx.x;
    const int c = threadIdx.x;
    const float n = (float)(NC * NL);
    const float mu = sums[2 * b] / n;
    const float var = sums[2 * b + 1] / n - mu * mu;
    const float rs = rsqrtf(var + 1e-6f);

    const f32x4* tv = (const f32x4*)(tin + b * NE);
    const f32x4* wA = (const f32x4*)(fw + (size_t)c * NE);
    const f32x4* wB = (const f32x4*)(fw + (size_t)(NC + c) * NE);
    float sc = 0.f, sh = 0.f;
#pragma unroll
    for (int e = 0; e < NE / 4; ++e) {
        f32x4 tq = tv[e], aq = wA[e], bq = wB[e];
        sc += tq[0] * aq[0] + tq[1] * aq[1] + tq[2] * aq[2] + tq[3] * aq[3];
        sh += tq[0] * bq[0] + tq[1] * bq[1] + tq[2] * bq[2] + tq[3] * bq[3];
    }
    sc += fb[c];
    sh += fb[NC + c];
    const float A = rs * (1.f + sc);
    afilm[b * NC + c] = A;
    bfilm[b * NC + c] = sh - mu * A;
}

// ---------------- K3: fused yn -> GEMM1(relu) -> GEMM2 -> residual ----------
// grid: B * (L/64) blocks, 256 threads = 4 waves.
// v4: SINGLE hs buffer -> LDS 51.2 KB -> 3 blocks/CU by LDS (160/51.2).
//     NO min-occupancy launch_bounds (Round-2 lesson: cap 168 caused spills;
//     this body compiles to ~108 VGPR at cap 256, under the 170 needed for
//     3 waves/SIMD, so 3 blocks arrive naturally).
//     BARSYNC = lgkmcnt-only barrier: weight prefetch (vmcnt) stays in
//     flight across barriers instead of draining to 0 twice per chunk.
__global__ __launch_bounds__(256, 2) void k3_gemm(
    const short* __restrict__ ynt, const short* __restrict__ pw1b,
    const short* __restrict__ pw2b, const float* __restrict__ pb1,
    const float* __restrict__ pb2, const float* __restrict__ afilm,
    const float* __restrict__ bfilm, const float* __restrict__ gamma,
    const float* __restrict__ x, float* __restrict__ out) {
    __shared__ short yn[64 * 264];   // [l][c], stride 264 : 33792 B
    __shared__ short hs[64 * 136];   // [l][d], stride 136 : 17408 B ; total 51200 B

    const int b = blockIdx.x >> 6;
    const int l0 = (blockIdx.x & 63) << 6;
    const int t = threadIdx.x;
    const int lane = t & 63, wid = t >> 6;
    const int ln = lane & 15, quad = lane >> 4;

    // ---- stage yn tile with the fused GroupNorm+FiLM affine ----
    {
        const int c8 = (t & 31) * 8;
        const int lrow = t >> 5;
        const f32x4 a0 = *(const f32x4*)(afilm + b * NC + c8);
        const f32x4 a1 = *(const f32x4*)(afilm + b * NC + c8 + 4);
        const f32x4 f0 = *(const f32x4*)(bfilm + b * NC + c8);
        const f32x4 f1 = *(const f32x4*)(bfilm + b * NC + c8 + 4);
        const short* ys = ynt + ((size_t)(b * NL + l0)) * NC + c8;
#pragma unroll
        for (int p = 0; p < 8; ++p) {
            const int l = p * 8 + lrow;
            s16x8 v = *(const s16x8*)(ys + (size_t)l * NC);
            s16x8 o;
#pragma unroll
            for (int j = 0; j < 4; ++j) {
                o[j]     = f2bf(a0[j] * bf2f(v[j])     + f0[j]);
                o[4 + j] = f2bf(a1[j] * bf2f(v[4 + j]) + f1[j]);
            }
            *(s16x8*)(yn + l * 264 + c8) = o;
        }
    }

    const short* A1b = pw1b + (size_t)(32 * wid + ln) * NC + quad * 8;
    const short* A2b = pw2b + (size_t)(64 * wid + ln) * NH + quad * 8;

    // A1(0): first half issued before the barrier (stays in flight across it)
    s16x8 a1p[16];
#pragma unroll
    for (int kk = 0; kk < 4; ++kk) {
        a1p[2 * kk + 0] = *(const s16x8*)(A1b + kk * 32);
        a1p[2 * kk + 1] = *(const s16x8*)(A1b + 16 * NC + kk * 32);
    }
    BARSYNC();   // yn ready (LDS only; global loads ride across)
#pragma unroll
    for (int kk = 4; kk < 8; ++kk) {
        a1p[2 * kk + 0] = *(const s16x8*)(A1b + kk * 32);
        a1p[2 * kk + 1] = *(const s16x8*)(A1b + 16 * NC + kk * 32);
    }

    // ---- GEMM1(0) ----
    f32x4 acc1[2][4] = {};
    __builtin_amdgcn_s_setprio(1);
#pragma unroll
    for (int kk = 0; kk < 8; ++kk) {
        const int kq = kk * 32 + quad * 8;
        s16x8 b0 = *(const s16x8*)(yn + (0 * 16 + ln) * 264 + kq);
        s16x8 b1 = *(const s16x8*)(yn + (1 * 16 + ln) * 264 + kq);
        s16x8 b2 = *(const s16x8*)(yn + (2 * 16 + ln) * 264 + kq);
        s16x8 b3 = *(const s16x8*)(yn + (3 * 16 + ln) * 264 + kq);
        acc1[0][0] = MFMA16(a1p[2 * kk], b0, acc1[0][0]);
        acc1[0][1] = MFMA16(a1p[2 * kk], b1, acc1[0][1]);
        acc1[0][2] = MFMA16(a1p[2 * kk], b2, acc1[0][2]);
        acc1[0][3] = MFMA16(a1p[2 * kk], b3, acc1[0][3]);
        acc1[1][0] = MFMA16(a1p[2 * kk + 1], b0, acc1[1][0]);
        acc1[1][1] = MFMA16(a1p[2 * kk + 1], b1, acc1[1][1]);
        acc1[1][2] = MFMA16(a1p[2 * kk + 1], b2, acc1[1][2]);
        acc1[1][3] = MFMA16(a1p[2 * kk + 1], b3, acc1[1][3]);
    }
    __builtin_amdgcn_s_setprio(0);

    f32x4 acc2[4][4] = {};

#pragma unroll 1
    for (int ch = 0; ch < 8; ++ch) {
        const int dc0 = ch * 128;
        // ---- A2(ch) loads: issued before hs-write, stay in flight across barA
        s16x8 a2p[16];
        const short* A2 = A2b + dc0;
#pragma unroll
        for (int kk = 0; kk < 4; ++kk) {
#pragma unroll
            for (int m = 0; m < 4; ++m) {
                a2p[4 * kk + m] = *(const s16x8*)(A2 + m * 16 * NH + kk * 32);
            }
        }
        // ---- hs <- relu(acc1 + b1) ----
#pragma unroll
        for (int mf = 0; mf < 2; ++mf) {
            const int dbase = 32 * wid + mf * 16 + quad * 4;
            const f32x4 b1v = *(const f32x4*)(pb1 + dc0 + dbase);
#pragma unroll
            for (int nf = 0; nf < 4; ++nf) {
                const int l = nf * 16 + ln;
                s16x4 hv;
#pragma unroll
                for (int r = 0; r < 4; ++r) {
                    hv[r] = f2bf(fmaxf(acc1[mf][nf][r] + b1v[r], 0.f));
                }
                *(s16x4*)(hs + l * 136 + dbase) = hv;
            }
        }
        BARSYNC();   // barA: hs ready; a2p loads NOT drained here

        // ---- A1(ch+1) first half (in flight under GEMM2) ----
        const short* A1n = A1b + (size_t)(dc0 + 128) * NC;
        if (ch < 7) {
#pragma unroll
            for (int kk = 0; kk < 4; ++kk) {
                a1p[2 * kk + 0] = *(const s16x8*)(A1n + kk * 32);
                a1p[2 * kk + 1] = *(const s16x8*)(A1n + 16 * NC + kk * 32);
            }
        }
        // ---- GEMM2(ch): acc2 += pw2[:, chunk] . h ----
        __builtin_amdgcn_s_setprio(1);
#pragma unroll
        for (int kk = 0; kk < 4; ++kk) {
            const int kq = kk * 32 + quad * 8;
            s16x8 h0 = *(const s16x8*)(hs + (0 * 16 + ln) * 136 + kq);
            s16x8 h1 = *(const s16x8*)(hs + (1 * 16 + ln) * 136 + kq);
            s16x8 h2 = *(const s16x8*)(hs + (2 * 16 + ln) * 136 + kq);
            s16x8 h3 = *(const s16x8*)(hs + (3 * 16 + ln) * 136 + kq);
            acc2[0][0] = MFMA16(a2p[4 * kk + 0], h0, acc2[0][0]);
            acc2[0][1] = MFMA16(a2p[4 * kk + 0], h1, acc2[0][1]);
            acc2[0][2] = MFMA16(a2p[4 * kk + 0], h2, acc2[0][2]);
            acc2[0][3] = MFMA16(a2p[4 * kk + 0], h3, acc2[0][3]);
            acc2[1][0] = MFMA16(a2p[4 * kk + 1], h0, acc2[1][0]);
            acc2[1][1] = MFMA16(a2p[4 * kk + 1], h1, acc2[1][1]);
            acc2[1][2] = MFMA16(a2p[4 * kk + 1], h2, acc2[1][2]);
            acc2[1][3] = MFMA16(a2p[4 * kk + 1], h3, acc2[1][3]);
            acc2[2][0] = MFMA16(a2p[4 * kk + 2], h0, acc2[2][0]);
            acc2[2][1] = MFMA16(a2p[4 * kk + 2], h1, acc2[2][1]);
            acc2[2][2] = MFMA16(a2p[4 * kk + 2], h2, acc2[2][2]);
            acc2[2][3] = MFMA16(a2p[4 * kk + 2], h3, acc2[2][3]);
            acc2[3][0] = MFMA16(a2p[4 * kk + 3], h0, acc2[3][0]);
            acc2[3][1] = MFMA16(a2p[4 * kk + 3], h1, acc2[3][1]);
            acc2[3][2] = MFMA16(a2p[4 * kk + 3], h2, acc2[3][2]);
            acc2[3][3] = MFMA16(a2p[4 * kk + 3], h3, acc2[3][3]);
        }
        __builtin_amdgcn_s_setprio(0);
        // ---- A1(ch+1) second half ----
        if (ch < 7) {
#pragma unroll
            for (int kk = 4; kk < 8; ++kk) {
                a1p[2 * kk + 0] = *(const s16x8*)(A1n + kk * 32);
                a1p[2 * kk + 1] = *(const s16x8*)(A1n + 16 * NC + kk * 32);
            }
        }
        BARSYNC();   // barB: hs consumed by all waves

        // ---- GEMM1(ch+1) ----
        if (ch < 7) {
#pragma unroll
            for (int i = 0; i < 2; ++i)
#pragma unroll
                for (int j = 0; j < 4; ++j) acc1[i][j] = (f32x4){0.f, 0.f, 0.f, 0.f};
            __builtin_amdgcn_s_setprio(1);
#pragma unroll
            for (int kk = 0; kk < 8; ++kk) {
                const int kq = kk * 32 + quad * 8;
                s16x8 b0 = *(const s16x8*)(yn + (0 * 16 + ln) * 264 + kq);
                s16x8 b1 = *(const s16x8*)(yn + (1 * 16 + ln) * 264 + kq);
                s16x8 b2 = *(const s16x8*)(yn + (2 * 16 + ln) * 264 + kq);
                s16x8 b3 = *(const s16x8*)(yn + (3 * 16 + ln) * 264 + kq);
                acc1[0][0] = MFMA16(a1p[2 * kk], b0, acc1[0][0]);
                acc1[0][1] = MFMA16(a1p[2 * kk], b1, acc1[0][1]);
                acc1[0][2] = MFMA16(a1p[2 * kk], b2, acc1[0][2]);
                acc1[0][3] = MFMA16(a1p[2 * kk], b3, acc1[0][3]);
                acc1[1][0] = MFMA16(a1p[2 * kk + 1], b0, acc1[1][0]);
                acc1[1][1] = MFMA16(a1p[2 * kk + 1], b1, acc1[1][1]);
                acc1[1][2] = MFMA16(a1p[2 * kk + 1], b2, acc1[1][2]);
                acc1[1][3] = MFMA16(a1p[2 * kk + 1], b3, acc1[1][3]);
            }
            __builtin_amdgcn_s_setprio(0);
        }
    }

    // ---- epilogue: out = x + gamma * (acc2 + b2) ----
#pragma unroll
    for (int mf2 = 0; mf2 < 4; ++mf2) {
        const int cbase = 64 * wid + mf2 * 16 + quad * 4;
        const f32x4 g4 = *(const f32x4*)(gamma + cbase);
        const f32x4 b4 = *(const f32x4*)(pb2 + cbase);
#pragma unroll
        for (int r = 0; r < 4; ++r) {
            const int c = cbase + r;
            const size_t base = ((size_t)(b * NC + c)) * NL + l0 + ln;
            const float* xr = x + base;
            float* orow = out + base;
#pragma unroll
            for (int nf2 = 0; nf2 < 4; ++nf2) {
                orow[nf2 * 16] = xr[nf2 * 16] + g4[r] * (acc2[mf2][nf2][r] + b4[r]);
            }
        }
    }
}

extern "C" void kernel_launch(void* const* d_in, const int* in_sizes, int n_in,
                              void* d_out, int out_size, void* d_ws, size_t ws_size,
                              hipStream_t stream) {
    (void)in_sizes; (void)n_in; (void)out_size; (void)ws_size;
    const float* x      = (const float*)d_in[0];
    const float* tin    = (const float*)d_in[1];
    const float* dw_w   = (const float*)d_in[2];
    const float* dw_b   = (const float*)d_in[3];
    const float* film_w = (const float*)d_in[4];
    const float* film_b = (const float*)d_in[5];
    const float* pw1_w  = (const float*)d_in[6];
    const float* pw1_b  = (const float*)d_in[7];
    const float* pw2_w  = (const float*)d_in[8];
    const float* pw2_b  = (const float*)d_in[9];
    const float* gamma  = (const float*)d_in[10];
    float* out = (float*)d_out;

    char* ws = (char*)d_ws;
    short* ynt  = (short*)(ws + WS_YNT);
    short* pw1b = (short*)(ws + WS_PW1);
    short* pw2b = (short*)(ws + WS_PW2);
    float* afilm = (float*)(ws + WS_AF);
    float* bfilm = (float*)(ws + WS_BF);
    float* sums  = (float*)(ws + WS_SUMS);

    hipLaunchKernelGGL(k0_prep, dim3(1024), dim3(256), 0, stream,
                       pw1_w, pw2_w, pw1b, pw2b, sums);
    hipLaunchKernelGGL(k1_dwconv, dim3(NB * 256), dim3(256), 0, stream,
                       x, dw_w, dw_b, ynt, sums);
    hipLaunchKernelGGL(k2_finalize, dim3(NB), dim3(256), 0, stream,
                       tin, film_w, film_b, sums, afilm, bfilm);
    hipLaunchKernelGGL(k3_gemm, dim3(NB * (NL / 64)), dim3(256), 0, stream,
                       ynt, pw1b, pw2b, pw1_b, pw2_b, afilm, bfilm, gamma, x, out);
}

// Round 5
// 275.439 us; speedup vs baseline: 1.3079x; 1.3079x over previous
//
#include <hip/hip_runtime.h>

typedef short s16x8 __attribute__((ext_vector_type(8)));
typedef short s16x4 __attribute__((ext_vector_type(4)));
typedef float f32x4 __attribute__((ext_vector_type(4)));

#define NB 16
#define NC 256
#define NL 4096
#define NH 1024
#define NE 128

// ws layout (bytes)
#define WS_YNT   0ull          // [B][L][C] bf16 transposed y   : 33554432
#define WS_PW1   33554432ull   // pw1 bf16 [1024][256]          : 524288
#define WS_PW2   34078720ull   // pw2 bf16 [256][1024]          : 524288
#define WS_AF    34603008ull   // a_film  [B][C] f32            : 16384
#define WS_BF    34619392ull   // b_film  [B][C] f32            : 16384
// per-block stat partials live in the first 32 KB of `out` (k3 fully
// overwrites out afterwards, stream-ordered) -> zero extra workspace.

#define MFMA16(a, b, c) __builtin_amdgcn_mfma_f32_16x16x32_bf16((a), (b), (c), 0, 0, 0)

static __device__ __forceinline__ short f2bf(float f) {
    unsigned int u = __float_as_uint(f);
    u = (u + 0x7fffu + ((u >> 16) & 1u)) >> 16;
    return (short)u;
}
static __device__ __forceinline__ float bf2f(short s) {
    return __uint_as_float(((unsigned int)(unsigned short)s) << 16);
}

// ---------------- K0: weight convert ----------------
__global__ __launch_bounds__(256) void k0_prep(const float* __restrict__ pw1,
                                               const float* __restrict__ pw2,
                                               short* __restrict__ pw1b,
                                               short* __restrict__ pw2b) {
    int idx = blockIdx.x * 256 + threadIdx.x;
    if (idx < NH * NC) {
        pw1b[idx] = f2bf(pw1[idx]);
        pw2b[idx] = f2bf(pw2[idx]);
    }
}

// ---------------- K1: depthwise conv (circular) + transpose-store + stats ----
// grid: B * 4 * 64 blocks; tile = (b, 64 c, 64 l). 256 threads.
// v5: NO global atomics (8192 same-line device atomics serialized ~100us).
//     Each block stores one float2 partial into psum[blockIdx]; k2 reduces.
__global__ __launch_bounds__(256) void k1_dwconv(const float* __restrict__ x,
                                                 const float* __restrict__ dw_w,
                                                 const float* __restrict__ dw_b,
                                                 short* __restrict__ ynt,
                                                 float2* __restrict__ psum) {
    __shared__ float xt[64][81];   // bank stride 81%32=17 (odd) -> <=2-way, free
    __shared__ float red1[4], red2[4];
    const int b = blockIdx.x >> 8;
    const int rem = blockIdx.x & 255;
    const int c0 = (rem >> 6) << 6;   // 4 c-blocks of 64
    const int l0 = (rem & 63) << 6;   // 64 l-blocks of 64
    const int t = threadIdx.x;

    // ---- stage 64 rows x 80 floats, coalesced float4 global loads ----
    const float* xb = x + ((size_t)(b * NC + c0)) * NL;
    {
#pragma unroll
        for (int j = 0; j < 5; ++j) {
            const int idx = t + 256 * j;
            const int row = idx / 20;
            const int col = idx - row * 20;
            const int lg = (l0 - 4 + col * 4) & (NL - 1);   // circular, 16B-aligned
            const float4 v = *(const float4*)(xb + (size_t)row * NL + lg);
            xt[row][col * 4 + 0] = v.x;
            xt[row][col * 4 + 1] = v.y;
            xt[row][col * 4 + 2] = v.z;
            xt[row][col * 4 + 3] = v.w;
        }
    }

    const int c = t & 63;       // lane == channel within tile
    const int w = t >> 6;       // wave id -> 16-l strip
    const float w0 = dw_w[(c0 + c) * 7 + 0], w1 = dw_w[(c0 + c) * 7 + 1],
                w2 = dw_w[(c0 + c) * 7 + 2], w3 = dw_w[(c0 + c) * 7 + 3],
                w4 = dw_w[(c0 + c) * 7 + 4], w5 = dw_w[(c0 + c) * 7 + 5],
                w6 = dw_w[(c0 + c) * 7 + 6];
    const float bb = dw_b[c0 + c];
    __syncthreads();

    float win0 = xt[c][w * 16 + 1], win1 = xt[c][w * 16 + 2], win2 = xt[c][w * 16 + 3],
          win3 = xt[c][w * 16 + 4], win4 = xt[c][w * 16 + 5], win5 = xt[c][w * 16 + 6],
          win6 = xt[c][w * 16 + 7];
    float s1 = 0.f, s2 = 0.f;
    short* yo = ynt + ((size_t)(b * NL + l0 + w * 16)) * NC + c0 + c;
#pragma unroll
    for (int i = 0; i < 16; ++i) {
        const float y = bb + w0 * win0 + w1 * win1 + w2 * win2 + w3 * win3 +
                        w4 * win4 + w5 * win5 + w6 * win6;
        s1 += y;
        s2 += y * y;
        yo[(size_t)i * NC] = f2bf(y);
        win0 = win1; win1 = win2; win2 = win3; win3 = win4; win4 = win5; win5 = win6;
        win6 = xt[c][w * 16 + i + 8];
    }
    for (int off = 32; off; off >>= 1) {
        s1 += __shfl_down(s1, off, 64);
        s2 += __shfl_down(s2, off, 64);
    }
    if ((t & 63) == 0) { red1[w] = s1; red2[w] = s2; }
    __syncthreads();
    if (t == 0) {
        psum[blockIdx.x] = make_float2(red1[0] + red1[1] + red1[2] + red1[3],
                                       red2[0] + red2[1] + red2[2] + red2[3]);
    }
}

// ---------------- K2: reduce partials + FiLM -> per-(b,c) affine --------------
__global__ __launch_bounds__(256) void k2_finalize(const float* __restrict__ tin,
                                                   const float* __restrict__ fw,
                                                   const float* __restrict__ fb,
                                                   const float2* __restrict__ psum,
                                                   float* __restrict__ afilm,
                                                   float* __restrict__ bfilm) {
    __shared__ float r1[4], r2[4];
    const int b = blockIdx.x;
    const int c = threadIdx.x;

    // reduce this batch's 256 block partials
    const float2 v = psum[b * 256 + c];
    float s1 = v.x, s2 = v.y;
    for (int off = 32; off; off >>= 1) {
        s1 += __shfl_down(s1, off, 64);
        s2 += __shfl_down(s2, off, 64);
    }
    if ((c & 63) == 0) { r1[c >> 6] = s1; r2[c >> 6] = s2; }
    __syncthreads();
    const float sum1 = r1[0] + r1[1] + r1[2] + r1[3];
    const float sum2 = r2[0] + r2[1] + r2[2] + r2[3];

    const float n = (float)(NC * NL);
    const float mu = sum1 / n;
    const float var = sum2 / n - mu * mu;
    const float rs = rsqrtf(var + 1e-6f);

    const f32x4* tv = (const f32x4*)(tin + b * NE);
    const f32x4* wA = (const f32x4*)(fw + (size_t)c * NE);
    const f32x4* wB = (const f32x4*)(fw + (size_t)(NC + c) * NE);
    float sc = 0.f, sh = 0.f;
#pragma unroll
    for (int e = 0; e < NE / 4; ++e) {
        f32x4 tq = tv[e], aq = wA[e], bq = wB[e];
        sc += tq[0] * aq[0] + tq[1] * aq[1] + tq[2] * aq[2] + tq[3] * aq[3];
        sh += tq[0] * bq[0] + tq[1] * bq[1] + tq[2] * bq[2] + tq[3] * bq[3];
    }
    sc += fb[c];
    sh += fb[NC + c];
    const float A = rs * (1.f + sc);
    afilm[b * NC + c] = A;
    bfilm[b * NC + c] = sh - mu * A;
}

// ---------------- K3: fused yn -> GEMM1(relu) -> GEMM2 -> residual ----------
// grid: B * (L/64) blocks, 256 threads = 4 waves.
// PROVEN 145.5us Round-0 body: double-buffered hs, ONE barrier per chunk,
// GEMM2(ch) interleaved with GEMM1(ch+1) in a single inter-barrier region.
__global__ __launch_bounds__(256, 2) void k3_gemm(
    const short* __restrict__ ynt, const short* __restrict__ pw1b,
    const short* __restrict__ pw2b, const float* __restrict__ pb1,
    const float* __restrict__ pb2, const float* __restrict__ afilm,
    const float* __restrict__ bfilm, const float* __restrict__ gamma,
    const float* __restrict__ x, float* __restrict__ out) {
    __shared__ short yn[64 * 264];      // [l][c], stride 264 (132 words == 4 mod 32)
    __shared__ short hs[2][64 * 136];   // [l][d], stride 136 (68 words  == 4 mod 32)

    const int b = blockIdx.x >> 6;
    const int l0 = (blockIdx.x & 63) << 6;
    const int t = threadIdx.x;
    const int lane = t & 63, wid = t >> 6;
    const int ln = lane & 15, quad = lane >> 4;

    // ---- stage yn tile with the fused GroupNorm+FiLM affine ----
    {
        const int c8 = (t & 31) * 8;
        const int lrow = t >> 5;
        const f32x4 a0 = *(const f32x4*)(afilm + b * NC + c8);
        const f32x4 a1 = *(const f32x4*)(afilm + b * NC + c8 + 4);
        const f32x4 f0 = *(const f32x4*)(bfilm + b * NC + c8);
        const f32x4 f1 = *(const f32x4*)(bfilm + b * NC + c8 + 4);
        const short* ys = ynt + ((size_t)(b * NL + l0)) * NC + c8;
#pragma unroll
        for (int p = 0; p < 8; ++p) {
            const int l = p * 8 + lrow;
            s16x8 v = *(const s16x8*)(ys + (size_t)l * NC);
            s16x8 o;
#pragma unroll
            for (int j = 0; j < 4; ++j) {
                o[j]     = f2bf(a0[j] * bf2f(v[j])     + f0[j]);
                o[4 + j] = f2bf(a1[j] * bf2f(v[4 + j]) + f1[j]);
            }
            *(s16x8*)(yn + l * 264 + c8) = o;
        }
    }

    const short* A1b = pw1b + (size_t)(32 * wid + ln) * NC + quad * 8;
    const short* A2b = pw2b + (size_t)(64 * wid + ln) * NH + quad * 8;

    // A1(0) first half issued before the barrier (drained during it)
    s16x8 a1p[16];
#pragma unroll
    for (int kk = 0; kk < 4; ++kk) {
        a1p[2 * kk + 0] = *(const s16x8*)(A1b + kk * 32);
        a1p[2 * kk + 1] = *(const s16x8*)(A1b + 16 * NC + kk * 32);
    }
    __syncthreads();   // yn ready
#pragma unroll
    for (int kk = 4; kk < 8; ++kk) {
        a1p[2 * kk + 0] = *(const s16x8*)(A1b + kk * 32);
        a1p[2 * kk + 1] = *(const s16x8*)(A1b + 16 * NC + kk * 32);
    }

    // ---- GEMM1(0) ----
    f32x4 acc1[2][4] = {};
#pragma unroll
    for (int kk = 0; kk < 8; ++kk) {
        const int kq = kk * 32 + quad * 8;
        s16x8 b0 = *(const s16x8*)(yn + (0 * 16 + ln) * 264 + kq);
        s16x8 b1 = *(const s16x8*)(yn + (1 * 16 + ln) * 264 + kq);
        s16x8 b2 = *(const s16x8*)(yn + (2 * 16 + ln) * 264 + kq);
        s16x8 b3 = *(const s16x8*)(yn + (3 * 16 + ln) * 264 + kq);
        acc1[0][0] = MFMA16(a1p[2 * kk], b0, acc1[0][0]);
        acc1[0][1] = MFMA16(a1p[2 * kk], b1, acc1[0][1]);
        acc1[0][2] = MFMA16(a1p[2 * kk], b2, acc1[0][2]);
        acc1[0][3] = MFMA16(a1p[2 * kk], b3, acc1[0][3]);
        acc1[1][0] = MFMA16(a1p[2 * kk + 1], b0, acc1[1][0]);
        acc1[1][1] = MFMA16(a1p[2 * kk + 1], b1, acc1[1][1]);
        acc1[1][2] = MFMA16(a1p[2 * kk + 1], b2, acc1[1][2]);
        acc1[1][3] = MFMA16(a1p[2 * kk + 1], b3, acc1[1][3]);
    }

    f32x4 acc2[4][4] = {};

#pragma unroll 1
    for (int ch = 0; ch < 7; ++ch) {
        const int dc0 = ch * 128;
        // ---- A2(ch) loads: in flight across hs-write, drained at the barrier
        s16x8 a2p[16];
        const short* A2 = A2b + dc0;
#pragma unroll
        for (int kk = 0; kk < 4; ++kk) {
#pragma unroll
            for (int m = 0; m < 4; ++m) {
                a2p[4 * kk + m] = *(const s16x8*)(A2 + m * 16 * NH + kk * 32);
            }
        }
        // ---- hs[ch&1] <- relu(acc1 + b1) ----
        short* hw = &hs[ch & 1][0];
#pragma unroll
        for (int mf = 0; mf < 2; ++mf) {
            const int dbase = 32 * wid + mf * 16 + quad * 4;
            const f32x4 b1v = *(const f32x4*)(pb1 + dc0 + dbase);
#pragma unroll
            for (int nf = 0; nf < 4; ++nf) {
                const int l = nf * 16 + ln;
                s16x4 hv;
#pragma unroll
                for (int r = 0; r < 4; ++r) {
                    hv[r] = f2bf(fmaxf(acc1[mf][nf][r] + b1v[r], 0.f));
                }
                *(s16x4*)(hw + l * 136 + dbase) = hv;
            }
        }
        __syncthreads();   // hs[ch&1] visible; a2p loads drained here
        // ---- A1(ch+1) first half ----
        const short* A1n = A1b + (size_t)(dc0 + 128) * NC;
#pragma unroll
        for (int kk = 0; kk < 4; ++kk) {
            a1p[2 * kk + 0] = *(const s16x8*)(A1n + kk * 32);
            a1p[2 * kk + 1] = *(const s16x8*)(A1n + 16 * NC + kk * 32);
        }
        // ---- GEMM2(ch): acc2 += pw2[:, chunk] . h ----
        const short* hr = &hs[ch & 1][0];
#pragma unroll
        for (int kk = 0; kk < 4; ++kk) {
            const int kq = kk * 32 + quad * 8;
            s16x8 h0 = *(const s16x8*)(hr + (0 * 16 + ln) * 136 + kq);
            s16x8 h1 = *(const s16x8*)(hr + (1 * 16 + ln) * 136 + kq);
            s16x8 h2 = *(const s16x8*)(hr + (2 * 16 + ln) * 136 + kq);
            s16x8 h3 = *(const s16x8*)(hr + (3 * 16 + ln) * 136 + kq);
            acc2[0][0] = MFMA16(a2p[4 * kk + 0], h0, acc2[0][0]);
            acc2[0][1] = MFMA16(a2p[4 * kk + 0], h1, acc2[0][1]);
            acc2[0][2] = MFMA16(a2p[4 * kk + 0], h2, acc2[0][2]);
            acc2[0][3] = MFMA16(a2p[4 * kk + 0], h3, acc2[0][3]);
            acc2[1][0] = MFMA16(a2p[4 * kk + 1], h0, acc2[1][0]);
            acc2[1][1] = MFMA16(a2p[4 * kk + 1], h1, acc2[1][1]);
            acc2[1][2] = MFMA16(a2p[4 * kk + 1], h2, acc2[1][2]);
            acc2[1][3] = MFMA16(a2p[4 * kk + 1], h3, acc2[1][3]);
            acc2[2][0] = MFMA16(a2p[4 * kk + 2], h0, acc2[2][0]);
            acc2[2][1] = MFMA16(a2p[4 * kk + 2], h1, acc2[2][1]);
            acc2[2][2] = MFMA16(a2p[4 * kk + 2], h2, acc2[2][2]);
            acc2[2][3] = MFMA16(a2p[4 * kk + 2], h3, acc2[2][3]);
            acc2[3][0] = MFMA16(a2p[4 * kk + 3], h0, acc2[3][0]);
            acc2[3][1] = MFMA16(a2p[4 * kk + 3], h1, acc2[3][1]);
            acc2[3][2] = MFMA16(a2p[4 * kk + 3], h2, acc2[3][2]);
            acc2[3][3] = MFMA16(a2p[4 * kk + 3], h3, acc2[3][3]);
        }
        // ---- A1(ch+1) second half ----
#pragma unroll
        for (int kk = 4; kk < 8; ++kk) {
            a1p[2 * kk + 0] = *(const s16x8*)(A1n + kk * 32);
            a1p[2 * kk + 1] = *(const s16x8*)(A1n + 16 * NC + kk * 32);
        }
        // ---- GEMM1(ch+1) ----
#pragma unroll
        for (int i = 0; i < 2; ++i)
#pragma unroll
            for (int j = 0; j < 4; ++j) acc1[i][j] = (f32x4){0.f, 0.f, 0.f, 0.f};
#pragma unroll
        for (int kk = 0; kk < 8; ++kk) {
            const int kq = kk * 32 + quad * 8;
            s16x8 b0 = *(const s16x8*)(yn + (0 * 16 + ln) * 264 + kq);
            s16x8 b1 = *(const s16x8*)(yn + (1 * 16 + ln) * 264 + kq);
            s16x8 b2 = *(const s16x8*)(yn + (2 * 16 + ln) * 264 + kq);
            s16x8 b3 = *(const s16x8*)(yn + (3 * 16 + ln) * 264 + kq);
            acc1[0][0] = MFMA16(a1p[2 * kk], b0, acc1[0][0]);
            acc1[0][1] = MFMA16(a1p[2 * kk], b1, acc1[0][1]);
            acc1[0][2] = MFMA16(a1p[2 * kk], b2, acc1[0][2]);
            acc1[0][3] = MFMA16(a1p[2 * kk], b3, acc1[0][3]);
            acc1[1][0] = MFMA16(a1p[2 * kk + 1], b0, acc1[1][0]);
            acc1[1][1] = MFMA16(a1p[2 * kk + 1], b1, acc1[1][1]);
            acc1[1][2] = MFMA16(a1p[2 * kk + 1], b2, acc1[1][2]);
            acc1[1][3] = MFMA16(a1p[2 * kk + 1], b3, acc1[1][3]);
        }
    }

    // ---- tail: chunk 7 GEMM2 ----
    {
        const int dc0 = 7 * 128;
        s16x8 a2p[16];
        const short* A2 = A2b + dc0;
#pragma unroll
        for (int kk = 0; kk < 4; ++kk) {
#pragma unroll
            for (int m = 0; m < 4; ++m) {
                a2p[4 * kk + m] = *(const s16x8*)(A2 + m * 16 * NH + kk * 32);
            }
        }
        short* hw = &hs[1][0];
#pragma unroll
        for (int mf = 0; mf < 2; ++mf) {
            const int dbase = 32 * wid + mf * 16 + quad * 4;
            const f32x4 b1v = *(const f32x4*)(pb1 + dc0 + dbase);
#pragma unroll
            for (int nf = 0; nf < 4; ++nf) {
                const int l = nf * 16 + ln;
                s16x4 hv;
#pragma unroll
                for (int r = 0; r < 4; ++r) {
                    hv[r] = f2bf(fmaxf(acc1[mf][nf][r] + b1v[r], 0.f));
                }
                *(s16x4*)(hw + l * 136 + dbase) = hv;
            }
        }
        __syncthreads();
        const short* hr = &hs[1][0];
#pragma unroll
        for (int kk = 0; kk < 4; ++kk) {
            const int kq = kk * 32 + quad * 8;
            s16x8 h0 = *(const s16x8*)(hr + (0 * 16 + ln) * 136 + kq);
            s16x8 h1 = *(const s16x8*)(hr + (1 * 16 + ln) * 136 + kq);
            s16x8 h2 = *(const s16x8*)(hr + (2 * 16 + ln) * 136 + kq);
            s16x8 h3 = *(const s16x8*)(hr + (3 * 16 + ln) * 136 + kq);
            acc2[0][0] = MFMA16(a2p[4 * kk + 0], h0, acc2[0][0]);
            acc2[0][1] = MFMA16(a2p[4 * kk + 0], h1, acc2[0][1]);
            acc2[0][2] = MFMA16(a2p[4 * kk + 0], h2, acc2[0][2]);
            acc2[0][3] = MFMA16(a2p[4 * kk + 0], h3, acc2[0][3]);
            acc2[1][0] = MFMA16(a2p[4 * kk + 1], h0, acc2[1][0]);
            acc2[1][1] = MFMA16(a2p[4 * kk + 1], h1, acc2[1][1]);
            acc2[1][2] = MFMA16(a2p[4 * kk + 1], h2, acc2[1][2]);
            acc2[1][3] = MFMA16(a2p[4 * kk + 1], h3, acc2[1][3]);
            acc2[2][0] = MFMA16(a2p[4 * kk + 2], h0, acc2[2][0]);
            acc2[2][1] = MFMA16(a2p[4 * kk + 2], h1, acc2[2][1]);
            acc2[2][2] = MFMA16(a2p[4 * kk + 2], h2, acc2[2][2]);
            acc2[2][3] = MFMA16(a2p[4 * kk + 2], h3, acc2[2][3]);
            acc2[3][0] = MFMA16(a2p[4 * kk + 3], h0, acc2[3][0]);
            acc2[3][1] = MFMA16(a2p[4 * kk + 3], h1, acc2[3][1]);
            acc2[3][2] = MFMA16(a2p[4 * kk + 3], h2, acc2[3][2]);
            acc2[3][3] = MFMA16(a2p[4 * kk + 3], h3, acc2[3][3]);
        }
    }

    // ---- epilogue: out = x + gamma * (acc2 + b2) ----
#pragma unroll
    for (int mf2 = 0; mf2 < 4; ++mf2) {
        const int cbase = 64 * wid + mf2 * 16 + quad * 4;
        const f32x4 g4 = *(const f32x4*)(gamma + cbase);
        const f32x4 b4 = *(const f32x4*)(pb2 + cbase);
#pragma unroll
        for (int r = 0; r < 4; ++r) {
            const int c = cbase + r;
            const size_t base = ((size_t)(b * NC + c)) * NL + l0 + ln;
            const float* xr = x + base;
            float* orow = out + base;
#pragma unroll
            for (int nf2 = 0; nf2 < 4; ++nf2) {
                orow[nf2 * 16] = xr[nf2 * 16] + g4[r] * (acc2[mf2][nf2][r] + b4[r]);
            }
        }
    }
}

extern "C" void kernel_launch(void* const* d_in, const int* in_sizes, int n_in,
                              void* d_out, int out_size, void* d_ws, size_t ws_size,
                              hipStream_t stream) {
    (void)in_sizes; (void)n_in; (void)out_size; (void)ws_size;
    const float* x      = (const float*)d_in[0];
    const float* tin    = (const float*)d_in[1];
    const float* dw_w   = (const float*)d_in[2];
    const float* dw_b   = (const float*)d_in[3];
    const float* film_w = (const float*)d_in[4];
    const float* film_b = (const float*)d_in[5];
    const float* pw1_w  = (const float*)d_in[6];
    const float* pw1_b  = (const float*)d_in[7];
    const float* pw2_w  = (const float*)d_in[8];
    const float* pw2_b  = (const float*)d_in[9];
    const float* gamma  = (const float*)d_in[10];
    float* out = (float*)d_out;

    char* ws = (char*)d_ws;
    short* ynt  = (short*)(ws + WS_YNT);
    short* pw1b = (short*)(ws + WS_PW1);
    short* pw2b = (short*)(ws + WS_PW2);
    float* afilm = (float*)(ws + WS_AF);
    float* bfilm = (float*)(ws + WS_BF);
    // stat partials: first 32 KB of out (k3 overwrites all of out later)
    float2* psum = (float2*)d_out;

    hipLaunchKernelGGL(k0_prep, dim3(1024), dim3(256), 0, stream,
                       pw1_w, pw2_w, pw1b, pw2b);
    hipLaunchKernelGGL(k1_dwconv, dim3(NB * 256), dim3(256), 0, stream,
                       x, dw_w, dw_b, ynt, psum);
    hipLaunchKernelGGL(k2_finalize, dim3(NB), dim3(256), 0, stream,
                       tin, film_w, film_b, psum, afilm, bfilm);
    hipLaunchKernelGGL(k3_gemm, dim3(NB * (NL / 64)), dim3(256), 0, stream,
                       ynt, pw1b, pw2b, pw1_b, pw2_b, afilm, bfilm, gamma, x, out);
}